// Round 5
// baseline (126.471 us; speedup 1.0000x reference)
//
#include <hip/hip_runtime.h>

namespace {

constexpr int Bn    = 10;
constexpr int H     = 320;
constexpr int W     = 1024;
constexpr int PTS   = 500;
constexpr int DENSE = 2000;
constexpr int N     = Bn * PTS;   // 5000 rows
constexpr int HWp   = H * W;
constexpr int KITER = 10;

// disp window: rows cy-7..cy+7, cols cx-11..cx+12 (padded to 24)
constexpr int WY   = 15;
constexpr int WX   = 24;
constexpr int WSZ  = WY * WX;       // 360 words
constexpr int WOFF = 7 * WX + 11;   // center offset inside the window

// One block (256 thr = 4 waves) per row. Validity is computed per-wave with
// no LDS and no barriers; ~78% of blocks exit before touching disp windows,
// bx/by (80 MB stream), or any __syncthreads.
__global__ __launch_bounds__(256, 6)
void rsbsp_kernel(const float* __restrict__ disp,
                  const float* __restrict__ forepred,
                  const int*   __restrict__ centerx,
                  const int*   __restrict__ centery,
                  const int*   __restrict__ bx,
                  const int*   __restrict__ by,
                  float*       __restrict__ out)
{
    __shared__ float win[WSZ];      // 15x24 disp window
    __shared__ float cmb0[4][3];    // per-wave {mx, mn, tot}
    __shared__ float cmb[2][4][2];  // [parity][wave][{sumL, cnt}]

    const int t    = threadIdx.x;
    const int wid  = t >> 6;
    const int lane = t & 63;
    const int row  = blockIdx.x;    // 0..4999
    const int b    = row / PTS;
    const int cx   = centerx[row];
    const int cy   = centery[row];
    const float* db = disp     + b * HWp;
    const float* fb = forepred + b * HWp;

    // ---- validity, per-wave, barrier-free: lanes 0..8 each compute one
    //      sobel-x tap of the 3x3 maxpool window (centers >=11 from borders,
    //      so SAME padding / border-zeroing are unreachable), then wave-max.
    float v = 0.f;
    if (lane < 9) {
        const int dy = lane / 3, dx = lane % 3;
        const float* fp = fb + (cy - 2 + dy) * W + (cx - 2 + dx);
        const float g = (fp[2]         - fp[0])
                + 2.f * (fp[W + 2]     - fp[W])
                +       (fp[2 * W + 2] - fp[2 * W]);
        v = fabsf(g);
    }
    #pragma unroll
    for (int m = 1; m < 16; m <<= 1) v = fmaxf(v, __shfl_xor(v, m));
    v = __shfl(v, 0, 64);           // lanes 0..15 all hold the tap max

    const float dcen = db[cy * W + cx];   // uniform address -> 1 line
    const float mgv  = fmaxf(v * ((dcen > 0.007f) ? 1.f : 0.f), 3.f) - 3.f;
    const bool validRow = mgv > 0.1f;     // block-uniform (same inputs per wave)

    if (!validRow) {
        // Reference: out = km * keep with keep=0; km is provably finite here
        // (Large cluster always retains the max sample), so exact zeros match.
        if (t == 0) { out[row * 2 + 0] = 0.f; out[row * 2 + 1] = 0.f; }
        return;                      // no barrier crossed on this path
    }

    // ---- valid path: issue bx/by int4 loads FIRST (HBM latency hides under
    //      window staging + barrier), then stage the 15x24 disp window.
    const int4* bx4 = reinterpret_cast<const int4*>(bx + row * DENSE);
    const int4* by4 = reinterpret_cast<const int4*>(by + row * DENSE);
    int4 xb0 = make_int4(0, 0, 0, 0), yb0 = xb0, xb1 = xb0, yb1 = xb0;
    xb0 = bx4[t]; yb0 = by4[t];                       // t < 256 <= 500: all active
    const bool q1on = (t + 256) < DENSE / 4;          // threads 0..243
    if (q1on) { xb1 = bx4[t + 256]; yb1 = by4[t + 256]; }

    const int gbase = (cy - 7) * W + (cx - 11);
    {
        const unsigned r0 = (unsigned)t / 24u, c0 = (unsigned)t - r0 * 24u;
        win[t] = db[gbase + r0 * W + c0];
        const int i1 = t + 256;
        if (i1 < WSZ) {
            const unsigned r1 = (unsigned)i1 / 24u, c1 = (unsigned)i1 - r1 * 24u;
            win[i1] = db[gbase + r1 * W + c1];
        }
    }
    __syncthreads();

    // ---- gather 2000 samples (8/thread) from the LDS window
    float s[8];
    float mx, mn, tot;
    {
        const float x0 = win[yb0.x * WX + xb0.x + WOFF];
        const float x1 = win[yb0.y * WX + xb0.y + WOFF];
        const float x2 = win[yb0.z * WX + xb0.z + WOFF];
        const float x3 = win[yb0.w * WX + xb0.w + WOFF];
        s[0] = x0; s[1] = x1; s[2] = x2; s[3] = x3;
        mx = fmaxf(fmaxf(x0, x1), fmaxf(x2, x3));
        mn = fminf(fminf(x0, x1), fminf(x2, x3));
        tot = (x0 + x1) + (x2 + x3);
    }
    if (q1on) {
        const float x0 = win[yb1.x * WX + xb1.x + WOFF];
        const float x1 = win[yb1.y * WX + xb1.y + WOFF];
        const float x2 = win[yb1.z * WX + xb1.z + WOFF];
        const float x3 = win[yb1.w * WX + xb1.w + WOFF];
        s[4] = x0; s[5] = x1; s[6] = x2; s[7] = x3;
        mx = fmaxf(mx, fmaxf(fmaxf(x0, x1), fmaxf(x2, x3)));
        mn = fminf(mn, fminf(fminf(x0, x1), fminf(x2, x3)));
        tot += (x0 + x1) + (x2 + x3);
    } else {
        // -INF sentinel: never >= mid (finite or NaN) -> contributes nothing
        // to the Large cluster, exactly like absent samples.
        s[4] = -INFINITY; s[5] = -INFINITY; s[6] = -INFINITY; s[7] = -INFINITY;
    }

    // wave butterfly then cross-wave LDS combine for {mx, mn, tot}
    #pragma unroll
    for (int m = 1; m < 64; m <<= 1) {
        mx  = fmaxf(mx, __shfl_xor(mx, m));
        mn  = fminf(mn, __shfl_xor(mn, m));
        tot += __shfl_xor(tot, m);
    }
    if (lane == 0) { cmb0[wid][0] = mx; cmb0[wid][1] = mn; cmb0[wid][2] = tot; }
    __syncthreads();
    mx  = fmaxf(fmaxf(cmb0[0][0], cmb0[1][0]), fmaxf(cmb0[2][0], cmb0[3][0]));
    mn  = fminf(fminf(cmb0[0][1], cmb0[1][1]), fminf(cmb0[2][1], cmb0[3][1]));
    tot = (cmb0[0][2] + cmb0[1][2]) + (cmb0[2][2] + cmb0[3][2]);

    // ---- 2-means via midpoint threshold (mL>=mS invariant: |x-mL|<=|x-mS|
    //      <=> x>=mid; tie->Large matches `<=`; NaN mid -> all-false matches
    //      the reference's NaN-compare path). sumS = tot - sumL.
    //      (cnt,sumL) repeating is a fixed point -> remaining iterations are
    //      bit-identical; finalize immediately with exact divisions.
    float mL = mx, mS = mn;
    float cntLast = 0.f;
    float prevSum = -1.f, prevCnt = -1.f;   // unreachable sentinels
    #pragma unroll 1
    for (int it = 0; it < KITER; ++it) {
        const float mid = 0.5f * (mL + mS);
        float sumL = 0.f;
        int   cw   = 0;
        #pragma unroll
        for (int j = 0; j < 8; ++j) {
            const float x  = s[j];
            const bool  bl = x >= mid;
            sumL += bl ? x : 0.f;
            cw   += (int)__popcll(__ballot(bl));   // wave-wide count, SALU
        }
        #pragma unroll
        for (int m = 1; m < 64; m <<= 1) sumL += __shfl_xor(sumL, m);

        const int par = it & 1;                    // parity dbuf: 1 barrier/iter
        if (lane == 0) { cmb[par][wid][0] = sumL; cmb[par][wid][1] = (float)cw; }
        __syncthreads();
        sumL = (cmb[par][0][0] + cmb[par][1][0]) + (cmb[par][2][0] + cmb[par][3][0]);
        const float cf = (cmb[par][0][1] + cmb[par][1][1]) + (cmb[par][2][1] + cmb[par][3][1]);
        const float df = (float)DENSE - cf;

        const bool done = (it == KITER - 1) || (cf == prevCnt && sumL == prevSum);
        if (done) {
            mL = sumL / cf;                        // exact div for outputs
            mS = (tot - sumL) / df;
            // cnt==0: sumL=+0 -> 0/0=NaN matches ref. cnt==DENSE: force NaN
            // (tot-sumL may be +-eps -> +-inf otherwise).
            if (cf == (float)DENSE) mS = __int_as_float(0x7fc00000);
            cntLast = cf;
            break;
        }
        mL = sumL * __builtin_amdgcn_rcpf(cf);     // fast rcp for intermediates
        mS = (tot - sumL) * __builtin_amdgcn_rcpf(df);
        prevSum = sumL; prevCnt = cf;
    }

    if (t == 0) {
        const bool contrast = ((mL - mS) > 0.005f) && (cntLast > 5.f);
        const float keep = contrast ? 1.f : 0.f;   // validRow already true
        // multiply (not select) so NaN cluster means propagate as in ref
        out[row * 2 + 0] = mL * keep;
        out[row * 2 + 1] = mS * keep;
    }
}

} // namespace

extern "C" void kernel_launch(void* const* d_in, const int* in_sizes, int n_in,
                              void* d_out, int out_size, void* d_ws, size_t ws_size,
                              hipStream_t stream) {
    const float* disp = (const float*)d_in[0];
    const float* fore = (const float*)d_in[1];
    const int*   cx   = (const int*)d_in[2];
    const int*   cy   = (const int*)d_in[3];
    const int*   bxp  = (const int*)d_in[4];
    const int*   byp  = (const int*)d_in[5];
    float* out = (float*)d_out;

    rsbsp_kernel<<<N, 256, 0, stream>>>(disp, fore, cx, cy, bxp, byp, out);
}

// Round 6
// 125.613 us; speedup vs baseline: 1.0068x; 1.0068x over previous
//
#include <hip/hip_runtime.h>

namespace {

constexpr int Bn    = 10;
constexpr int H     = 320;
constexpr int W     = 1024;
constexpr int PTS   = 500;
constexpr int DENSE = 2000;
constexpr int N     = Bn * PTS;   // 5000 rows
constexpr int HWp   = H * W;
constexpr int KITER = 10;
constexpr int RPB   = 4;          // one row per wave, 4 waves per block

// disp window: rows cy-7..cy+7, cols cx-11..cx+12 (padded to 24)
constexpr int WY   = 15;
constexpr int WX   = 24;
constexpr int WSZ  = WY * WX;       // 360 words = 1440 B per wave
constexpr int WOFF = 7 * WX + 11;   // center offset inside the window

// 1250 blocks x 256 threads; each WAVE owns one row end-to-end. No barriers
// anywhere: per-wave LDS slice, same-wave DS ops are in-order (validated in
// round 3, absmax 0.0). Invalid rows (~78%) exit after the validity probe.
// 16 independent row-chains per CU hide the L3-latency row-setup loads.
__global__ __launch_bounds__(256, 4)
void rsbsp_kernel(const float* __restrict__ disp,
                  const float* __restrict__ forepred,
                  const int*   __restrict__ centerx,
                  const int*   __restrict__ centery,
                  const int*   __restrict__ bx,
                  const int*   __restrict__ by,
                  float*       __restrict__ out)
{
    __shared__ float win[RPB][WSZ];

    const int wid  = threadIdx.x >> 6;
    const int lane = threadIdx.x & 63;
    const int row  = blockIdx.x * RPB + wid;   // 0..4999
    const int b    = row / PTS;
    const int cx   = centerx[row];
    const int cy   = centery[row];
    const float* db = disp     + b * HWp;
    const float* fb = forepred + b * HWp;

    // ---- validity, per-wave, barrier-free: lanes 0..8 each compute one
    //      sobel-x tap of the 3x3 maxpool window (centers >=11 from borders,
    //      so SAME padding / border-zeroing are unreachable), then wave-max.
    float v = 0.f;
    if (lane < 9) {
        const int dy = lane / 3, dx = lane % 3;
        const float* fp = fb + (cy - 2 + dy) * W + (cx - 2 + dx);
        const float g = (fp[2]         - fp[0])
                + 2.f * (fp[W + 2]     - fp[W])
                +       (fp[2 * W + 2] - fp[2 * W]);
        v = fabsf(g);
    }
    #pragma unroll
    for (int m = 1; m < 16; m <<= 1) v = fmaxf(v, __shfl_xor(v, m));
    v = __shfl(v, 0, 64);

    const float dcen = db[cy * W + cx];   // uniform address -> 1 line
    const float mgv  = fmaxf(v * ((dcen > 0.007f) ? 1.f : 0.f), 3.f) - 3.f;
    const bool validRow = mgv > 0.1f;     // wave-uniform

    if (!validRow) {
        // Reference: out = km * keep with keep=0; km is provably finite here
        // (Large cluster always retains the max sample), so exact zeros match.
        if (lane == 0) { out[row * 2 + 0] = 0.f; out[row * 2 + 1] = 0.f; }
        return;                            // wave-level exit, no barriers exist
    }

    // ---- valid path: stage the 15x24 disp window into this wave's LDS slice
    float* wl = win[wid];
    const int gbase = (cy - 7) * W + (cx - 11);
    #pragma unroll
    for (int i = 0; i < 6; ++i) {
        const int w = lane + 64 * i;
        if (w < WSZ) {
            const unsigned r = (unsigned)w / 24u;
            const unsigned c = (unsigned)w - r * 24u;
            wl[w] = db[gbase + r * W + c];
        }
    }

    // ---- gather 2000 samples (32/lane) from the LDS window; bx/by as int4.
    //      Same-wave ds_write -> ds_read: in-order per wave, no barrier needed.
    const int4* bx4 = reinterpret_cast<const int4*>(bx + row * DENSE);
    const int4* by4 = reinterpret_cast<const int4*>(by + row * DENSE);

    float s[32];
    float mx = -INFINITY, mn = INFINITY, tot = 0.f;
    #pragma unroll
    for (int k = 0; k < 8; ++k) {
        const int q = lane + 64 * k;        // int4 index, 500 total
        if (q < DENSE / 4) {                 // only k==7 partially masked
            const int4 xb = bx4[q];
            const int4 yb = by4[q];
            const float x0 = wl[yb.x * WX + xb.x + WOFF];
            const float x1 = wl[yb.y * WX + xb.y + WOFF];
            const float x2 = wl[yb.z * WX + xb.z + WOFF];
            const float x3 = wl[yb.w * WX + xb.w + WOFF];
            s[k * 4 + 0] = x0; s[k * 4 + 1] = x1;
            s[k * 4 + 2] = x2; s[k * 4 + 3] = x3;
            mx = fmaxf(fmaxf(fmaxf(mx, x0), fmaxf(x1, x2)), x3);
            mn = fminf(fminf(fminf(mn, x0), fminf(x1, x2)), x3);
            tot += (x0 + x1) + (x2 + x3);
        } else {
            // -INF sentinel: never >= mid (finite or NaN) -> contributes
            // nothing to the Large cluster, exactly like absent samples.
            s[k * 4 + 0] = -INFINITY; s[k * 4 + 1] = -INFINITY;
            s[k * 4 + 2] = -INFINITY; s[k * 4 + 3] = -INFINITY;
        }
    }

    // wave butterfly: all lanes end with row max/min/total
    #pragma unroll
    for (int m = 1; m < 64; m <<= 1) {
        mx  = fmaxf(mx, __shfl_xor(mx, m));
        mn  = fminf(mn, __shfl_xor(mn, m));
        tot += __shfl_xor(tot, m);
    }

    // ---- 2-means via midpoint threshold (mL>=mS invariant: |x-mL|<=|x-mS|
    //      <=> x>=mid; tie->Large matches `<=`; NaN mid -> all-false matches
    //      the reference's NaN-compare path). sumS = tot - sumL.
    //      (cnt,sumL) repeating is a fixed point -> remaining iterations are
    //      bit-identical; finalize immediately with exact divisions.
    float mL = mx, mS = mn;
    float cntLast = 0.f;
    float prevSum = -1.f, prevCnt = -1.f;   // unreachable sentinels
    #pragma unroll 1
    for (int it = 0; it < KITER; ++it) {
        const float mid = 0.5f * (mL + mS);
        float sumL = 0.f;
        int   cw   = 0;
        #pragma unroll
        for (int j = 0; j < 32; ++j) {
            const float x  = s[j];
            const bool  bl = x >= mid;
            sumL += bl ? x : 0.f;
            cw   += (int)__popcll(__ballot(bl));   // wave-wide count, SALU
        }
        #pragma unroll
        for (int m = 1; m < 64; m <<= 1) sumL += __shfl_xor(sumL, m);

        const float cf = (float)cw;
        const float df = (float)DENSE - cf;
        const bool done = (it == KITER - 1) || (cf == prevCnt && sumL == prevSum);
        if (done) {
            mL = sumL / cf;                        // exact div for outputs
            mS = (tot - sumL) / df;
            // cnt==0: sumL=+0 -> 0/0=NaN matches ref. cnt==DENSE: force NaN
            // (tot-sumL may be +-eps -> +-inf otherwise).
            if (cw == DENSE) mS = __int_as_float(0x7fc00000);
            cntLast = cf;
            break;
        }
        mL = sumL * __builtin_amdgcn_rcpf(cf);     // fast rcp for intermediates
        mS = (tot - sumL) * __builtin_amdgcn_rcpf(df);
        prevSum = sumL; prevCnt = cf;
    }

    if (lane == 0) {
        const bool contrast = ((mL - mS) > 0.005f) && (cntLast > 5.f);
        const float keep = contrast ? 1.f : 0.f;   // validRow already true
        // multiply (not select) so NaN cluster means propagate as in ref
        out[row * 2 + 0] = mL * keep;
        out[row * 2 + 1] = mS * keep;
    }
}

} // namespace

extern "C" void kernel_launch(void* const* d_in, const int* in_sizes, int n_in,
                              void* d_out, int out_size, void* d_ws, size_t ws_size,
                              hipStream_t stream) {
    const float* disp = (const float*)d_in[0];
    const float* fore = (const float*)d_in[1];
    const int*   cx   = (const int*)d_in[2];
    const int*   cy   = (const int*)d_in[3];
    const int*   bxp  = (const int*)d_in[4];
    const int*   byp  = (const int*)d_in[5];
    float* out = (float*)d_out;

    rsbsp_kernel<<<N / RPB, 256, 0, stream>>>(disp, fore, cx, cy, bxp, byp, out);
}